// Round 9
// baseline (988.506 us; speedup 1.0000x reference)
//
#include <hip/hip_runtime.h>
#include <stdint.h>

typedef unsigned short u16;
typedef __attribute__((ext_vector_type(8))) short bh8;   // 8 x bf16 (bits)
typedef __attribute__((ext_vector_type(4))) float f4;

__device__ __forceinline__ float b2f(u16 u){ union{unsigned u; float f;} x; x.u = ((unsigned)u)<<16; return x.f; }
__device__ __forceinline__ u16 f2b(float f){ union{float f; unsigned u;} x; x.f = f; return (u16)((x.u + 0x7fffu + ((x.u>>16)&1u))>>16); }
__device__ __forceinline__ bh8 ld8(const u16* p){ return *reinterpret_cast<const bh8*>(p); }

// ---------------- graph preprocessing ----------------
__global__ void k_count_deg(const int* dst, int* deg, int E){
  int i = blockIdx.x*256 + threadIdx.x;
  if (i < E) atomicAdd(&deg[dst[i]], 1);
}

__global__ __launch_bounds__(1024) void k_scan(const int* deg, int* off, int n){
  __shared__ int wsum[16];
  __shared__ int carry_s;
  int t = threadIdx.x, lane = t & 63, wv = t >> 6;
  if (t == 0) carry_s = 0;
  __syncthreads();
  for (int base = 0; base < n; base += 1024){
    int v = (base + t < n) ? deg[base + t] : 0;
    int x = v;
    #pragma unroll
    for (int o = 1; o < 64; o <<= 1){
      int u = __shfl_up(x, (unsigned)o, 64);
      if (lane >= o) x += u;
    }
    if (lane == 63) wsum[wv] = x;
    __syncthreads();
    if (wv == 0 && lane < 16){
      int s = wsum[lane];
      #pragma unroll
      for (int o = 1; o < 16; o <<= 1){
        int u = __shfl_up(s, (unsigned)o, 64);
        if (lane >= o) s += u;
      }
      wsum[lane] = s;
    }
    __syncthreads();
    int woff = (wv == 0) ? 0 : wsum[wv-1];
    int c = carry_s;
    if (base + t < n) off[base + t] = c + woff + x - v;
    __syncthreads();
    if (t == 0) carry_s = c + wsum[15];
    __syncthreads();
  }
  if (threadIdx.x == 0) off[n] = carry_s;
}

__global__ void k_invdeg(const int* deg, float* inv_deg, float* inv_sqrt, int n){
  int i = blockIdx.x*256 + threadIdx.x;
  if (i < n){
    int d = deg[i]; if (d < 1) d = 1;
    float df = (float)d;
    inv_deg[i] = 1.0f/df;
    inv_sqrt[i] = rsqrtf(df);
  }
}

__global__ void k_copy_int(const int* a, int* b, int n){
  int i = blockIdx.x*256 + threadIdx.x;
  if (i < n) b[i] = a[i];
}

// csr entry: (src, inv_sqrt[src])
__global__ void k_fill_csr(const int* src, const int* dst, const float* invs,
                           int* cursor, int2* csr, int E){
  int i = blockIdx.x*256 + threadIdx.x;
  if (i < E){
    int s = src[i];
    float w = invs[s];
    int p = atomicAdd(&cursor[dst[i]], 1);
    csr[p] = make_int2(s, __float_as_int(w));
  }
}

__global__ void k_softmax(const float* alphas, float* wmix){
  int t = threadIdx.x; int r = t >> 3, o = t & 7;
  if (r < 14){
    float v = alphas[r*8+o];
    float m = v;
    #pragma unroll
    for (int d=1; d<8; d<<=1) m = fmaxf(m, __shfl_xor(m, d, 8));
    float e = expf(v - m);
    float s = e;
    #pragma unroll
    for (int d=1; d<8; d<<=1) s += __shfl_xor(s, d, 8);
    wmix[r*8+o] = e / s;
  }
}

// ---------------- conversion / packing ----------------
__global__ void k_f2b(const float* a, u16* b, int n){
  int i = blockIdx.x*256 + threadIdx.x;
  if (i < n) b[i] = f2b(a[i]);
}

// W fp32 [K][ncol] row-major -> Bp bf16 [ncol][K]
__global__ void k_pack2d(const float* W, u16* Bp, int K, int ncol){
  int i = blockIdx.x*256 + threadIdx.x;
  if (i < K*ncol){
    int k = i / ncol, n = i - k*ncol;
    Bp[(size_t)n*K + k] = f2b(W[i]);
  }
}

// op weights with softmax-mix folding. 7 matrices per slot:
// 0: wv2*W_gcn (relu, s_norm)      1: wv3*W_self + wv5*W_gc1 + wv1*I (h, direct)
// 2: wv3*W_nei (s_mean)            3: wv4*W_gin (relu, h+s_sum)
// 4: wv5*W_gc2 (s_sum)             5: wv6*W_mlp (relu, h)
// 6: wv7*W_gcnii (relu, 0.9 s_norm + 0.1 x0)
struct PackArgs { const float* W[8]; const float* wmix; u16* dst; };
__global__ void k_pack_ops7(PackArgs P){
  int i = blockIdx.x*256 + threadIdx.x;
  if (i >= 28*7*4096) return;
  int slot28 = i / (7*4096);
  int rem = i % (7*4096);
  int mat = rem >> 12;
  int e = rem & 4095;
  int k = e >> 6, n = e & 63;
  const float* wm = P.wmix + (slot28 % 14)*8;
  size_t off = (size_t)slot28*4096 + e;   // source [28][64][64] row-major [k][n]
  float v = 0.f;
  switch(mat){
    case 0: v = wm[2]*P.W[0][off]; break;
    case 1: v = wm[3]*P.W[1][off] + wm[5]*P.W[4][off] + ((k==n) ? wm[1] : 0.f); break;
    case 2: v = wm[3]*P.W[2][off]; break;
    case 3: v = wm[4]*P.W[3][off]; break;
    case 4: v = wm[5]*P.W[5][off]; break;
    case 5: v = wm[6]*P.W[6][off]; break;
    case 6: v = wm[7]*P.W[7][off]; break;
  }
  P.dst[(((size_t)slot28*7 + mat)<<12) + (n<<6) + k] = f2b(v);
}

// classifier weight: fold pooling into W. Weff[n][k] = W[(1+k)*40+n] + W[n]/256
__global__ void k_pack_cls(const float* W, u16* Bp){
  int i = blockIdx.x*256 + threadIdx.x;
  if (i < 48*256){
    int n = i >> 8, k = i & 255;
    float v = 0.f;
    if (n < 40) v = W[(size_t)(1+k)*40 + n] + W[n] * (1.f/256.f);
    Bp[(size_t)n*256 + k] = f2b(v);
  }
}

// ---------------- MLP: GEMM (+fused BN stats) + normalize ----------------
template<int NT>
__global__ __launch_bounds__(256) void k_gemm(const u16* A, int lda, const u16* Bp, int K,
                                              u16* Tb, int ldT, int Nn, float* S){
  __shared__ float sred[4][NT*16][2];
  int tid = threadIdx.x, wv = tid>>6, lane = tid&63, q = lane>>4, t = lane&15;
  int row0 = blockIdx.x*128 + wv*32;
  f4 acc[2][NT];
  #pragma unroll
  for (int a=0;a<2;a++)
    #pragma unroll
    for (int b=0;b<NT;b++) acc[a][b] = (f4){0.f,0.f,0.f,0.f};
  int nkb = K >> 5;
  const u16* arow0 = A + (size_t)(row0 + t)*lda + q*8;
  const u16* arow1 = arow0 + (size_t)16*lda;
  const u16* brow  = Bp + (size_t)t*K + q*8;
  for (int kb = 0; kb < nkb; ++kb){
    bh8 a0 = ld8(arow0 + kb*32);
    bh8 a1 = ld8(arow1 + kb*32);
    #pragma unroll
    for (int nt=0; nt<NT; ++nt){
      bh8 bf = ld8(brow + (size_t)nt*16*K + kb*32);
      acc[0][nt] = __builtin_amdgcn_mfma_f32_16x16x32_bf16(a0, bf, acc[0][nt], 0, 0, 0);
      acc[1][nt] = __builtin_amdgcn_mfma_f32_16x16x32_bf16(a1, bf, acc[1][nt], 0, 0, 0);
    }
  }
  #pragma unroll
  for (int nt=0;nt<NT;nt++){
    float ps = 0.f, pq = 0.f;
    #pragma unroll
    for (int rt=0;rt<2;rt++)
      #pragma unroll
      for (int r=0;r<4;r++){
        int row = row0 + rt*16 + q*4 + r;
        float v = acc[rt][nt][r];
        if (row < Nn){
          Tb[(size_t)row*ldT + nt*16 + t] = f2b(v);
          ps += v; pq += v*v;
        }
      }
    ps += __shfl_xor(ps, 16, 64); pq += __shfl_xor(pq, 16, 64);
    ps += __shfl_xor(ps, 32, 64); pq += __shfl_xor(pq, 32, 64);
    if (q == 0){ sred[wv][nt*16 + t][0] = ps; sred[wv][nt*16 + t][1] = pq; }
  }
  __syncthreads();
  if (tid < NT*16){
    float s = sred[0][tid][0] + sred[1][tid][0] + sred[2][tid][0] + sred[3][tid][0];
    float qq = sred[0][tid][1] + sred[1][tid][1] + sred[2][tid][1] + sred[3][tid][1];
    atomicAdd(&S[tid], s);
    atomicAdd(&S[256 + tid], qq);
  }
}

__global__ void k_norm(const u16* Tb, int ldT, int ncols, int Nn, const float* S,
                       u16* out, int rs_out, int relu, float invN){
  int i = blockIdx.x*256 + threadIdx.x;
  int nv = ncols >> 3;
  if (i >= Nn*nv) return;
  int r = i / nv, c8 = (i - r*nv)*8;
  bh8 tv = ld8(Tb + (size_t)r*ldT + c8);
  bh8 ov;
  #pragma unroll
  for (int u=0; u<8; ++u){
    int c = c8 + u;
    float m = S[c]*invN;
    float var = S[256+c]*invN - m*m;
    float xv = (b2f((u16)tv[u]) - m) * rsqrtf(var + 1e-5f);
    if (relu) xv = fmaxf(xv, 0.f);
    ov[u] = (short)f2b(xv);
  }
  *reinterpret_cast<bh8*>(out + (size_t)r*rs_out + c8) = ov;
}

// ---------------- aggregation: 4 edges in flight, 8B chunks (r4-proven) ----------------
// lane = (sub = lane>>4 : edge, chunk = lane&15 : 4-channel group)
template<int SHIFT>
__global__ __launch_bounds__(256) void k_aggv(const u16* h, const int* off, const int2* csr,
                                              const float* inv_sqrt, u16* out_sum, u16* out_norm, int Nn){
  int g = blockIdx.x*4 + (threadIdx.x >> 6);
  if (g >= Nn) return;
  int lane = threadIdx.x & 63;
  int sub = lane >> 4;
  int cb = (lane & 15) << 2;
  const u16* hp = h + cb;
  float s0=0.f,s1=0.f,s2=0.f,s3=0.f;
  float n0=0.f,n1=0.f,n2=0.f,n3=0.f;
  int e0 = off[g], e1 = off[g+1];
  for (int e = e0 + sub; e < e1; e += 4){
    int2 ce = csr[e];
    float w = __int_as_float(ce.y);
    uint2 v = *reinterpret_cast<const uint2*>(hp + (((unsigned)ce.x) << SHIFT));
    float c0 = __uint_as_float(v.x << 16);
    float c1 = __uint_as_float(v.x & 0xffff0000u);
    float c2 = __uint_as_float(v.y << 16);
    float c3 = __uint_as_float(v.y & 0xffff0000u);
    s0 += c0; s1 += c1; s2 += c2; s3 += c3;
    n0 += c0*w; n1 += c1*w; n2 += c2*w; n3 += c3*w;
  }
  s0 += __shfl_xor(s0,16,64); s1 += __shfl_xor(s1,16,64);
  s2 += __shfl_xor(s2,16,64); s3 += __shfl_xor(s3,16,64);
  n0 += __shfl_xor(n0,16,64); n1 += __shfl_xor(n1,16,64);
  n2 += __shfl_xor(n2,16,64); n3 += __shfl_xor(n3,16,64);
  s0 += __shfl_xor(s0,32,64); s1 += __shfl_xor(s1,32,64);
  s2 += __shfl_xor(s2,32,64); s3 += __shfl_xor(s3,32,64);
  n0 += __shfl_xor(n0,32,64); n1 += __shfl_xor(n1,32,64);
  n2 += __shfl_xor(n2,32,64); n3 += __shfl_xor(n3,32,64);
  if (sub == 0){
    float ig = inv_sqrt[g];
    uint2 os, on;
    os.x = (uint)f2b(s0) | ((uint)f2b(s1) << 16);
    os.y = (uint)f2b(s2) | ((uint)f2b(s3) << 16);
    on.x = (uint)f2b(n0*ig) | ((uint)f2b(n1*ig) << 16);
    on.y = (uint)f2b(n2*ig) | ((uint)f2b(n3*ig) << 16);
    *reinterpret_cast<uint2*>(out_sum + (size_t)g*64 + cb) = os;
    *reinterpret_cast<uint2*>(out_norm + (size_t)g*64 + cb) = on;
  }
}

// dual-state over interleaved ab [N][128] (a at +0, b at +64) — r4-proven
__global__ __launch_bounds__(256) void k_agg2v(const u16* ab, const int* off, const int2* csr,
                                               const float* inv_sqrt,
                                               u16* os0, u16* on0, u16* os1, u16* on1, int Nn){
  int g = blockIdx.x*4 + (threadIdx.x >> 6);
  if (g >= Nn) return;
  int lane = threadIdx.x & 63;
  int sub = lane >> 4;
  int cb = (lane & 15) << 2;
  const u16* hp = ab + cb;
  float sa0=0.f,sa1=0.f,sa2=0.f,sa3=0.f, na0=0.f,na1=0.f,na2=0.f,na3=0.f;
  float sb0=0.f,sb1=0.f,sb2=0.f,sb3=0.f, nb0=0.f,nb1=0.f,nb2=0.f,nb3=0.f;
  int e0 = off[g], e1 = off[g+1];
  for (int e = e0 + sub; e < e1; e += 4){
    int2 ce = csr[e];
    float w = __int_as_float(ce.y);
    const u16* rp = hp + (((unsigned)ce.x) << 7);
    uint2 va = *reinterpret_cast<const uint2*>(rp);
    uint2 vb = *reinterpret_cast<const uint2*>(rp + 64);
    float a0 = __uint_as_float(va.x << 16);
    float a1 = __uint_as_float(va.x & 0xffff0000u);
    float a2 = __uint_as_float(va.y << 16);
    float a3 = __uint_as_float(va.y & 0xffff0000u);
    float b0 = __uint_as_float(vb.x << 16);
    float b1 = __uint_as_float(vb.x & 0xffff0000u);
    float b2 = __uint_as_float(vb.y << 16);
    float b3 = __uint_as_float(vb.y & 0xffff0000u);
    sa0 += a0; sa1 += a1; sa2 += a2; sa3 += a3;
    na0 += a0*w; na1 += a1*w; na2 += a2*w; na3 += a3*w;
    sb0 += b0; sb1 += b1; sb2 += b2; sb3 += b3;
    nb0 += b0*w; nb1 += b1*w; nb2 += b2*w; nb3 += b3*w;
  }
  #pragma unroll
  for (int m = 16; m <= 32; m <<= 1){
    sa0 += __shfl_xor(sa0,m,64); sa1 += __shfl_xor(sa1,m,64);
    sa2 += __shfl_xor(sa2,m,64); sa3 += __shfl_xor(sa3,m,64);
    na0 += __shfl_xor(na0,m,64); na1 += __shfl_xor(na1,m,64);
    na2 += __shfl_xor(na2,m,64); na3 += __shfl_xor(na3,m,64);
    sb0 += __shfl_xor(sb0,m,64); sb1 += __shfl_xor(sb1,m,64);
    sb2 += __shfl_xor(sb2,m,64); sb3 += __shfl_xor(sb3,m,64);
    nb0 += __shfl_xor(nb0,m,64); nb1 += __shfl_xor(nb1,m,64);
    nb2 += __shfl_xor(nb2,m,64); nb3 += __shfl_xor(nb3,m,64);
  }
  if (sub == 0){
    float ig = inv_sqrt[g];
    uint2 v;
    v.x = (uint)f2b(sa0) | ((uint)f2b(sa1) << 16);
    v.y = (uint)f2b(sa2) | ((uint)f2b(sa3) << 16);
    *reinterpret_cast<uint2*>(os0 + (size_t)g*64 + cb) = v;
    v.x = (uint)f2b(na0*ig) | ((uint)f2b(na1*ig) << 16);
    v.y = (uint)f2b(na2*ig) | ((uint)f2b(na3*ig) << 16);
    *reinterpret_cast<uint2*>(on0 + (size_t)g*64 + cb) = v;
    v.x = (uint)f2b(sb0) | ((uint)f2b(sb1) << 16);
    v.y = (uint)f2b(sb2) | ((uint)f2b(sb3) << 16);
    *reinterpret_cast<uint2*>(os1 + (size_t)g*64 + cb) = v;
    v.x = (uint)f2b(nb0*ig) | ((uint)f2b(nb1*ig) << 16);
    v.y = (uint)f2b(nb2*ig) | ((uint)f2b(nb3*ig) << 16);
    *reinterpret_cast<uint2*>(on1 + (size_t)g*64 + cb) = v;
  }
}

// ---------------- fused mixed-op step ----------------
struct StepArgs {
  const u16* h[5]; const u16* asum[5]; const u16* anorm[5];
  int rs[5]; int slot[5]; int J;
  const u16* wpk; const float* inv_deg; const u16* x0;
  u16* out; u16* out2; int rs_out; int Nn;   // out2: compact [N][64] copy for the next gather
};

__device__ __forceinline__ bh8 fr_scale(bh8 a, float s){
  bh8 r;
  #pragma unroll
  for (int i=0;i<8;i++) r[i] = (short)f2b(b2f((u16)a[i]) * s);
  return r;
}
__device__ __forceinline__ bh8 fr_add(bh8 a, bh8 b){
  bh8 r;
  #pragma unroll
  for (int i=0;i<8;i++) r[i] = (short)f2b(b2f((u16)a[i]) + b2f((u16)b[i]));
  return r;
}
__device__ __forceinline__ bh8 fr_comb(bh8 a, bh8 b, float wa, float wb){
  bh8 r;
  #pragma unroll
  for (int i=0;i<8;i++) r[i] = (short)f2b(wa*b2f((u16)a[i]) + wb*b2f((u16)b[i]));
  return r;
}

__device__ __forceinline__ void mm_acc(const bh8 (&af)[2][2], const u16* wlds, int mat,
                                       int t, int q, f4 (&oacc)[2][4]){
  #pragma unroll
  for (int kb=0;kb<2;kb++)
    #pragma unroll
    for (int nt=0;nt<4;nt++){
      bh8 bf = ld8(wlds + (mat<<12) + ((nt*16+t)<<6) + ((((kb<<2)|q) ^ (t&7))<<3));
      oacc[0][nt] = __builtin_amdgcn_mfma_f32_16x16x32_bf16(af[0][kb], bf, oacc[0][nt], 0, 0, 0);
      oacc[1][nt] = __builtin_amdgcn_mfma_f32_16x16x32_bf16(af[1][kb], bf, oacc[1][nt], 0, 0, 0);
    }
}

__device__ __forceinline__ void mm_relu(const bh8 (&af)[2][2], const u16* wlds, int mat,
                                        int t, int q, f4 (&oacc)[2][4]){
  f4 p[2][4];
  #pragma unroll
  for (int a=0;a<2;a++)
    #pragma unroll
    for (int b=0;b<4;b++) p[a][b] = (f4){0.f,0.f,0.f,0.f};
  #pragma unroll
  for (int kb=0;kb<2;kb++)
    #pragma unroll
    for (int nt=0;nt<4;nt++){
      bh8 bf = ld8(wlds + (mat<<12) + ((nt*16+t)<<6) + ((((kb<<2)|q) ^ (t&7))<<3));
      p[0][nt] = __builtin_amdgcn_mfma_f32_16x16x32_bf16(af[0][kb], bf, p[0][nt], 0, 0, 0);
      p[1][nt] = __builtin_amdgcn_mfma_f32_16x16x32_bf16(af[1][kb], bf, p[1][nt], 0, 0, 0);
    }
  #pragma unroll
  for (int rt=0;rt<2;rt++)
    #pragma unroll
    for (int nt=0;nt<4;nt++)
      #pragma unroll
      for (int r=0;r<4;r++)
        oacc[rt][nt][r] += fmaxf(p[rt][nt][r], 0.f);
}

__global__ __launch_bounds__(512) __attribute__((amdgpu_waves_per_eu(2,2)))
void k_step(StepArgs A){
  __shared__ u16 wlds[7*4096];   // 56 KB, XOR-swizzled 16B chunks
  int tid = threadIdx.x, wv = tid>>6, lane = tid&63, q = lane>>4, t = lane&15;
  int row0 = blockIdx.x*256 + wv*32;
  int rA0 = row0 + t, rA1 = row0 + 16 + t;
  int q8 = q*8;
  float idg0 = A.inv_deg[rA0];
  float idg1 = A.inv_deg[rA1];
  const u16* xp0 = A.x0 + (size_t)rA0*64;
  const u16* xp1 = A.x0 + (size_t)rA1*64;
  bh8 fx[2][2];
  fx[0][0]=ld8(xp0+q8); fx[0][1]=ld8(xp0+32+q8); fx[1][0]=ld8(xp1+q8); fx[1][1]=ld8(xp1+32+q8);

  f4 oacc[2][4];
  #pragma unroll
  for (int a=0;a<2;a++)
    #pragma unroll
    for (int b=0;b<4;b++) oacc[a][b] = (f4){0.f,0.f,0.f,0.f};

  for (int j = 0; j < A.J; ++j){
    __syncthreads();
    const u16* wg = A.wpk + ((size_t)A.slot[j]*7 << 12);
    for (int i = tid; i < 3584; i += 512){
      int mat = i >> 9, rem = i & 511, nn = rem >> 3, kc = rem & 7;
      uint4 vch = *reinterpret_cast<const uint4*>(wg + ((size_t)mat<<12) + (nn<<6) + (kc<<3));
      *reinterpret_cast<uint4*>(&wlds[(mat<<12) + (nn<<6) + ((kc ^ (nn&7))<<3)]) = vch;
    }
    __syncthreads();

    const u16* h = A.h[j]; int rs = A.rs[j];
    const u16* hp0 = h + (size_t)rA0*rs;
    const u16* hp1 = h + (size_t)rA1*rs;
    const u16* sp0 = A.asum[j] + (size_t)rA0*64;
    const u16* sp1 = A.asum[j] + (size_t)rA1*64;
    const u16* np0 = A.anorm[j] + (size_t)rA0*64;
    const u16* np1 = A.anorm[j] + (size_t)rA1*64;

    bh8 fh[2][2], fs[2][2], ax[2][2];

    fh[0][0]=ld8(hp0+q8); fh[0][1]=ld8(hp0+32+q8); fh[1][0]=ld8(hp1+q8); fh[1][1]=ld8(hp1+32+q8);
    mm_acc(fh, wlds, 1, t, q, oacc);
    mm_relu(fh, wlds, 5, t, q, oacc);
    fs[0][0]=ld8(sp0+q8); fs[0][1]=ld8(sp0+32+q8); fs[1][0]=ld8(sp1+q8); fs[1][1]=ld8(sp1+32+q8);
    mm_acc(fs, wlds, 4, t, q, oacc);
    ax[0][0]=fr_scale(fs[0][0], idg0); ax[0][1]=fr_scale(fs[0][1], idg0);
    ax[1][0]=fr_scale(fs[1][0], idg1); ax[1][1]=fr_scale(fs[1][1], idg1);
    mm_acc(ax, wlds, 2, t, q, oacc);
    ax[0][0]=fr_add(fh[0][0], fs[0][0]); ax[0][1]=fr_add(fh[0][1], fs[0][1]);
    ax[1][0]=fr_add(fh[1][0], fs[1][0]); ax[1][1]=fr_add(fh[1][1], fs[1][1]);
    mm_relu(ax, wlds, 3, t, q, oacc);
    fs[0][0]=ld8(np0+q8); fs[0][1]=ld8(np0+32+q8); fs[1][0]=ld8(np1+q8); fs[1][1]=ld8(np1+32+q8);
    mm_relu(fs, wlds, 0, t, q, oacc);
    ax[0][0]=fr_comb(fs[0][0], fx[0][0], 0.9f, 0.1f);
    ax[0][1]=fr_comb(fs[0][1], fx[0][1], 0.9f, 0.1f);
    ax[1][0]=fr_comb(fs[1][0], fx[1][0], 0.9f, 0.1f);
    ax[1][1]=fr_comb(fs[1][1], fx[1][1], 0.9f, 0.1f);
    mm_relu(ax, wlds, 6, t, q, oacc);
  }

  #pragma unroll
  for (int rt=0;rt<2;rt++)
    #pragma unroll
    for (int nt=0;nt<4;nt++)
      #pragma unroll
      for (int r=0;r<4;r++){
        int rr = row0 + rt*16 + q*4 + r;
        if (rr < A.Nn){
          u16 bv = f2b(oacc[rt][nt][r]);
          A.out[(size_t)rr*A.rs_out + nt*16 + t] = bv;
          if (A.out2) A.out2[(size_t)rr*64 + nt*16 + t] = bv;
        }
      }
}

// ---------------- classifier: MFMA GEMM [N,256]x[256,48] with bias ----------------
__global__ __launch_bounds__(256) void k_cls_mm(const u16* A, const u16* Bp,
                                                const float* bvec, float* out, int Nn){
  int tid = threadIdx.x, wv = tid>>6, lane = tid&63, q = lane>>4, t = lane&15;
  int row0 = blockIdx.x*128 + wv*32;
  f4 acc[2][3];
  #pragma unroll
  for (int a=0;a<2;a++)
    #pragma unroll
    for (int b=0;b<3;b++) acc[a][b] = (f4){0.f,0.f,0.f,0.f};
  const u16* arow0 = A + (size_t)(row0 + t)*256 + q*8;
  const u16* arow1 = arow0 + (size_t)16*256;
  const u16* brow  = Bp + (size_t)t*256 + q*8;
  #pragma unroll
  for (int kb = 0; kb < 8; ++kb){
    bh8 a0 = ld8(arow0 + kb*32);
    bh8 a1 = ld8(arow1 + kb*32);
    #pragma unroll
    for (int nt=0; nt<3; ++nt){
      bh8 bf = ld8(brow + (size_t)nt*16*256 + kb*32);
      acc[0][nt] = __builtin_amdgcn_mfma_f32_16x16x32_bf16(a0, bf, acc[0][nt], 0, 0, 0);
      acc[1][nt] = __builtin_amdgcn_mfma_f32_16x16x32_bf16(a1, bf, acc[1][nt], 0, 0, 0);
    }
  }
  #pragma unroll
  for (int rt=0;rt<2;rt++)
    #pragma unroll
    for (int nt=0;nt<3;nt++){
      int col = nt*16 + t;
      #pragma unroll
      for (int r=0;r<4;r++){
        int row = row0 + rt*16 + q*4 + r;
        if (row < Nn && col < 40) out[(size_t)row*40 + col] = acc[rt][nt][r] + bvec[col];
      }
    }
}

// ---------------- host ----------------
extern "C" void kernel_launch(void* const* d_in, const int* in_sizes, int n_in,
                              void* d_out, int out_size, void* d_ws, size_t ws_size,
                              hipStream_t stream){
  (void)n_in; (void)out_size; (void)ws_size;
  const float* x      = (const float*)d_in[0];
  const int*   ei     = (const int*)d_in[1];
  const float* alphas = (const float*)d_in[2];
  const float* stem_W = (const float*)d_in[3];
  const float* pre_W  = (const float*)d_in[4];
  const float* p00    = (const float*)d_in[5];
  const float* p10    = (const float*)d_in[6];
  const float* p01    = (const float*)d_in[7];
  const float* p11    = (const float*)d_in[8];
  const float* clsW = (const float*)d_in[17];
  const float* clsb = (const float*)d_in[18];

  int N = in_sizes[0] / 128;
  int E = in_sizes[1] / 2;
  const int* esrc = ei;
  const int* edst = ei + E;

  char* p = (char*)d_ws;
  auto carve = [&](size_t bytes) -> char* {
    char* r = p; p += (bytes + 255) & ~(size_t)255; return r;
  };
  int*   deg     = (int*)carve((size_t)N*4);
  int*   off     = (int*)carve((size_t)(N+1)*4);
  int*   cursor  = (int*)carve((size_t)N*4);
  int2*  csr     = (int2*)carve((size_t)E*8);
  float* inv_deg = (float*)carve((size_t)N*4);
  float* invs    = (float*)carve((size_t)N*4);
  float* wmix    = (float*)carve(14*8*4);
  float* stats   = (float*)carve(512*4);
  u16* xb      = (u16*)carve((size_t)N*128*2);
  u16* stem_pk = (u16*)carve((size_t)192*128*2);
  u16* pre_pk  = (u16*)carve((size_t)64*128*2);
  u16* p00_pk  = (u16*)carve((size_t)64*192*2);
  u16* p10_pk  = (u16*)carve((size_t)64*192*2);
  u16* p01_pk  = (u16*)carve((size_t)64*192*2);
  u16* p11_pk  = (u16*)carve((size_t)64*256*2);
  u16* cls_pk  = (u16*)carve((size_t)48*256*2);
  u16* ops_pk  = (u16*)carve((size_t)28*7*4096*2);
  u16* T       = (u16*)carve((size_t)N*192*2);
  u16* stem_o  = (u16*)carve((size_t)N*192*2);
  u16* x0b     = (u16*)carve((size_t)N*64*2);
  u16* ab      = (u16*)carve((size_t)N*128*2);
  u16* sc      = (u16*)carve((size_t)N*64*2);   // compact copy of the newest state
  u16* oc0     = (u16*)carve((size_t)N*256*2);
  u16* oc1     = (u16*)carve((size_t)N*256*2);
  u16* agg     = (u16*)carve((size_t)5*2*N*64*2);
  carve(131072); // tail slack for unguarded OOB-row reads

  auto aggS = [&](int j){ return agg + (size_t)j*2*N*64; };
  auto aggN = [&](int j){ return agg + (size_t)j*2*N*64 + (size_t)N*64; };

  int eg = (E + 255)/256;
  int ng = (N + 255)/256;
  int gg = (N + 127)/128;
  int gg2 = (N + 255)/256;
  int ag = (N + 3)/4;
  float invN = 1.0f/(float)N;

  hipMemsetAsync(deg, 0, (size_t)N*4, stream);
  k_count_deg<<<eg,256,0,stream>>>(edst, deg, E);
  k_scan<<<1,1024,0,stream>>>(deg, off, N);
  k_invdeg<<<ng,256,0,stream>>>(deg, inv_deg, invs, N);
  k_copy_int<<<ng,256,0,stream>>>(off, cursor, N);
  k_fill_csr<<<eg,256,0,stream>>>(esrc, edst, invs, cursor, csr, E);
  k_softmax<<<1,128,0,stream>>>(alphas, wmix);
  k_f2b<<<(N*128+255)/256,256,0,stream>>>(x, xb, N*128);
  k_pack2d<<<(128*192+255)/256,256,0,stream>>>(stem_W, stem_pk, 128, 192);
  k_pack2d<<<(128*64+255)/256,256,0,stream>>>(pre_W, pre_pk, 128, 64);
  k_pack2d<<<(192*64+255)/256,256,0,stream>>>(p00, p00_pk, 192, 64);
  k_pack2d<<<(192*64+255)/256,256,0,stream>>>(p10, p10_pk, 192, 64);
  k_pack2d<<<(192*64+255)/256,256,0,stream>>>(p01, p01_pk, 192, 64);
  k_pack2d<<<(256*64+255)/256,256,0,stream>>>(p11, p11_pk, 256, 64);
  k_pack_cls<<<(48*256+255)/256,256,0,stream>>>(clsW, cls_pk);
  {
    PackArgs PA;
    for (int i = 0; i < 8; ++i) PA.W[i] = (const float*)d_in[9+i];
    PA.wmix = wmix; PA.dst = ops_pk;
    k_pack_ops7<<<(28*7*4096+255)/256,256,0,stream>>>(PA);
  }

  auto mlp = [&](const u16* A, int lda, const u16* Bp, int K, int ncol, u16* outb, int rs_out, int relu){
    hipMemsetAsync(stats, 0, 512*4, stream);
    if (ncol == 192)
      hipLaunchKernelGGL(HIP_KERNEL_NAME(k_gemm<12>), dim3(gg), dim3(256), 0, stream, A, lda, Bp, K, T, ncol, N, stats);
    else
      hipLaunchKernelGGL(HIP_KERNEL_NAME(k_gemm<4>), dim3(gg), dim3(256), 0, stream, A, lda, Bp, K, T, ncol, N, stats);
    k_norm<<<((N*(ncol>>3))+255)/256,256,0,stream>>>(T, ncol, ncol, N, stats, outb, rs_out, relu, invN);
  };

  // stem (no relu) and preprocess (relu)
  mlp(xb, 128, stem_pk, 128, 192, stem_o, 192, 0);
  mlp(xb, 128, pre_pk, 128, 64, x0b, 64, 1);

  u16* ocs[2] = {oc0, oc1};
  const int slotbase[4] = {0, 2, 5, 9};
  for (int ci = 0; ci < 2; ++ci){
    const u16* s1in = (ci == 0) ? stem_o : oc0;
    int lda1 = (ci == 0) ? 192 : 256;
    int Kb   = (ci == 0) ? 192 : 256;
    const u16* pa = (ci == 0) ? p00_pk : p01_pk;
    const u16* pb = (ci == 0) ? p10_pk : p11_pk;
    mlp(stem_o, 192, pa, 192, 64, ab, 128, 1);        // a -> ab[:, 0:64]
    mlp(s1in, lda1, pb, Kb, 64, ab + 64, 128, 1);     // b -> ab[:, 64:128]

    u16* oc = ocs[ci];
    const u16* wpk_cell = ops_pk + (size_t)ci*14*7*4096;

    k_agg2v<<<ag,256,0,stream>>>(ab, off, csr, invs,
                                 aggS(0), aggN(0), aggS(1), aggN(1), N);

    const u16* st[5] = { ab, ab + 64, oc + 0, oc + 64, oc + 128 };
    const int strs[5] = {128, 128, 256, 256, 256};
    for (int step = 0; step < 4; ++step){
      StepArgs SA{};
      int J = step + 2;
      for (int j = 0; j < J; ++j){
        SA.h[j] = st[j]; SA.rs[j] = strs[j];
        SA.asum[j] = aggS(j); SA.anorm[j] = aggN(j);
        SA.slot[j] = slotbase[step] + j;
      }
      SA.J = J; SA.wpk = wpk_cell; SA.inv_deg = inv_deg; SA.x0 = x0b;
      SA.out = oc + (size_t)step*64; SA.out2 = (step < 3) ? sc : nullptr;
      SA.rs_out = 256; SA.Nn = N;
      k_step<<<gg2,512,0,stream>>>(SA);
      if (step < 3)
        hipLaunchKernelGGL(HIP_KERNEL_NAME(k_aggv<6>), dim3(ag), dim3(256), 0, stream,
                           sc, off, csr, invs, aggS(step+2), aggN(step+2), N);
    }
  }

  k_cls_mm<<<gg,256,0,stream>>>(oc1, cls_pk, clsb, (float*)d_out, N);
}

// Round 10
// 924.023 us; speedup vs baseline: 1.0698x; 1.0698x over previous
//
#include <hip/hip_runtime.h>
#include <stdint.h>

typedef unsigned short u16;
typedef __attribute__((ext_vector_type(8))) short bh8;   // 8 x bf16 (bits)
typedef __attribute__((ext_vector_type(4))) float f4;

__device__ __forceinline__ float b2f(u16 u){ union{unsigned u; float f;} x; x.u = ((unsigned)u)<<16; return x.f; }
__device__ __forceinline__ u16 f2b(float f){ union{float f; unsigned u;} x; x.f = f; return (u16)((x.u + 0x7fffu + ((x.u>>16)&1u))>>16); }
__device__ __forceinline__ bh8 ld8(const u16* p){ return *reinterpret_cast<const bh8*>(p); }

// ---------------- graph preprocessing ----------------
__global__ void k_count_deg(const int* dst, int* deg, int E){
  int i = blockIdx.x*256 + threadIdx.x;
  if (i < E) atomicAdd(&deg[dst[i]], 1);
}

__global__ __launch_bounds__(1024) void k_scan(const int* deg, int* off, int n){
  __shared__ int wsum[16];
  __shared__ int carry_s;
  int t = threadIdx.x, lane = t & 63, wv = t >> 6;
  if (t == 0) carry_s = 0;
  __syncthreads();
  for (int base = 0; base < n; base += 1024){
    int v = (base + t < n) ? deg[base + t] : 0;
    int x = v;
    #pragma unroll
    for (int o = 1; o < 64; o <<= 1){
      int u = __shfl_up(x, (unsigned)o, 64);
      if (lane >= o) x += u;
    }
    if (lane == 63) wsum[wv] = x;
    __syncthreads();
    if (wv == 0 && lane < 16){
      int s = wsum[lane];
      #pragma unroll
      for (int o = 1; o < 16; o <<= 1){
        int u = __shfl_up(s, (unsigned)o, 64);
        if (lane >= o) s += u;
      }
      wsum[lane] = s;
    }
    __syncthreads();
    int woff = (wv == 0) ? 0 : wsum[wv-1];
    int c = carry_s;
    if (base + t < n) off[base + t] = c + woff + x - v;
    __syncthreads();
    if (t == 0) carry_s = c + wsum[15];
    __syncthreads();
  }
  if (threadIdx.x == 0) off[n] = carry_s;
}

// deg -> inv_deg / inv_sqrt, plus cursor = off (fused copy)
__global__ void k_invdeg(const int* deg, const int* off, int* cursor,
                         float* inv_deg, float* inv_sqrt, int n){
  int i = blockIdx.x*256 + threadIdx.x;
  if (i < n){
    cursor[i] = off[i];
    int d = deg[i]; if (d < 1) d = 1;
    float df = (float)d;
    inv_deg[i] = 1.0f/df;
    inv_sqrt[i] = rsqrtf(df);
  }
}

// csr entry: (src, inv_sqrt[src])
__global__ void k_fill_csr(const int* src, const int* dst, const float* invs,
                           int* cursor, int2* csr, int E){
  int i = blockIdx.x*256 + threadIdx.x;
  if (i < E){
    int s = src[i];
    float w = invs[s];
    int p = atomicAdd(&cursor[dst[i]], 1);
    csr[p] = make_int2(s, __float_as_int(w));
  }
}

__global__ void k_softmax(const float* alphas, float* wmix){
  int t = threadIdx.x; int r = t >> 3, o = t & 7;
  if (r < 14){
    float v = alphas[r*8+o];
    float m = v;
    #pragma unroll
    for (int d=1; d<8; d<<=1) m = fmaxf(m, __shfl_xor(m, d, 8));
    float e = expf(v - m);
    float s = e;
    #pragma unroll
    for (int d=1; d<8; d<<=1) s += __shfl_xor(s, d, 8);
    wmix[r*8+o] = e / s;
  }
}

// ---------------- conversion / packing ----------------
__global__ void k_f2b(const float* a, u16* b, int n){
  int i = blockIdx.x*256 + threadIdx.x;
  if (i < n) b[i] = f2b(a[i]);
}

// W fp32 [K][ncol] row-major -> Bp bf16 [ncol][K]
__global__ void k_pack2d(const float* W, u16* Bp, int K, int ncol){
  int i = blockIdx.x*256 + threadIdx.x;
  if (i < K*ncol){
    int k = i / ncol, n = i - k*ncol;
    Bp[(size_t)n*K + k] = f2b(W[i]);
  }
}

// op weights with softmax-mix folding. 7 matrices per slot:
// 0: wv2*W_gcn (relu, s_norm)      1: wv3*W_self + wv5*W_gc1 + wv1*I (h, direct)
// 2: wv3*W_nei (s_mean)            3: wv4*W_gin (relu, h+s_sum)
// 4: wv5*W_gc2 (s_sum)             5: wv6*W_mlp (relu, h)
// 6: wv7*W_gcnii (relu, 0.9 s_norm + 0.1 x0)
struct PackArgs { const float* W[8]; const float* wmix; u16* dst; };
__global__ void k_pack_ops7(PackArgs P){
  int i = blockIdx.x*256 + threadIdx.x;
  if (i >= 28*7*4096) return;
  int slot28 = i / (7*4096);
  int rem = i % (7*4096);
  int mat = rem >> 12;
  int e = rem & 4095;
  int k = e >> 6, n = e & 63;
  const float* wm = P.wmix + (slot28 % 14)*8;
  size_t off = (size_t)slot28*4096 + e;   // source [28][64][64] row-major [k][n]
  float v = 0.f;
  switch(mat){
    case 0: v = wm[2]*P.W[0][off]; break;
    case 1: v = wm[3]*P.W[1][off] + wm[5]*P.W[4][off] + ((k==n) ? wm[1] : 0.f); break;
    case 2: v = wm[3]*P.W[2][off]; break;
    case 3: v = wm[4]*P.W[3][off]; break;
    case 4: v = wm[5]*P.W[5][off]; break;
    case 5: v = wm[6]*P.W[6][off]; break;
    case 6: v = wm[7]*P.W[7][off]; break;
  }
  P.dst[(((size_t)slot28*7 + mat)<<12) + (n<<6) + k] = f2b(v);
}

// classifier weight: fold pooling into W. Weff[n][k] = W[(1+k)*40+n] + W[n]/256
__global__ void k_pack_cls(const float* W, u16* Bp){
  int i = blockIdx.x*256 + threadIdx.x;
  if (i < 48*256){
    int n = i >> 8, k = i & 255;
    float v = 0.f;
    if (n < 40) v = W[(size_t)(1+k)*40 + n] + W[n] * (1.f/256.f);
    Bp[(size_t)n*256 + k] = f2b(v);
  }
}

// ---------------- MLP: GEMM (+fused BN stats) + normalize ----------------
template<int NT>
__global__ __launch_bounds__(256) void k_gemm(const u16* A, int lda, const u16* Bp, int K,
                                              u16* Tb, int ldT, int Nn, float* S){
  __shared__ float sred[4][NT*16][2];
  int tid = threadIdx.x, wv = tid>>6, lane = tid&63, q = lane>>4, t = lane&15;
  int row0 = blockIdx.x*128 + wv*32;
  f4 acc[2][NT];
  #pragma unroll
  for (int a=0;a<2;a++)
    #pragma unroll
    for (int b=0;b<NT;b++) acc[a][b] = (f4){0.f,0.f,0.f,0.f};
  int nkb = K >> 5;
  const u16* arow0 = A + (size_t)(row0 + t)*lda + q*8;
  const u16* arow1 = arow0 + (size_t)16*lda;
  const u16* brow  = Bp + (size_t)t*K + q*8;
  for (int kb = 0; kb < nkb; ++kb){
    bh8 a0 = ld8(arow0 + kb*32);
    bh8 a1 = ld8(arow1 + kb*32);
    #pragma unroll
    for (int nt=0; nt<NT; ++nt){
      bh8 bf = ld8(brow + (size_t)nt*16*K + kb*32);
      acc[0][nt] = __builtin_amdgcn_mfma_f32_16x16x32_bf16(a0, bf, acc[0][nt], 0, 0, 0);
      acc[1][nt] = __builtin_amdgcn_mfma_f32_16x16x32_bf16(a1, bf, acc[1][nt], 0, 0, 0);
    }
  }
  #pragma unroll
  for (int nt=0;nt<NT;nt++){
    float ps = 0.f, pq = 0.f;
    #pragma unroll
    for (int rt=0;rt<2;rt++)
      #pragma unroll
      for (int r=0;r<4;r++){
        int row = row0 + rt*16 + q*4 + r;
        float v = acc[rt][nt][r];
        if (row < Nn){
          Tb[(size_t)row*ldT + nt*16 + t] = f2b(v);
          ps += v; pq += v*v;
        }
      }
    ps += __shfl_xor(ps, 16, 64); pq += __shfl_xor(pq, 16, 64);
    ps += __shfl_xor(ps, 32, 64); pq += __shfl_xor(pq, 32, 64);
    if (q == 0){ sred[wv][nt*16 + t][0] = ps; sred[wv][nt*16 + t][1] = pq; }
  }
  __syncthreads();
  if (tid < NT*16){
    float s = sred[0][tid][0] + sred[1][tid][0] + sred[2][tid][0] + sred[3][tid][0];
    float qq = sred[0][tid][1] + sred[1][tid][1] + sred[2][tid][1] + sred[3][tid][1];
    atomicAdd(&S[tid], s);
    atomicAdd(&S[256 + tid], qq);
  }
}

__global__ void k_norm(const u16* Tb, int ldT, int ncols, int Nn, const float* S,
                       u16* out, int rs_out, int relu, float invN){
  int i = blockIdx.x*256 + threadIdx.x;
  int nv = ncols >> 3;
  if (i >= Nn*nv) return;
  int r = i / nv, c8 = (i - r*nv)*8;
  bh8 tv = ld8(Tb + (size_t)r*ldT + c8);
  bh8 ov;
  #pragma unroll
  for (int u=0; u<8; ++u){
    int c = c8 + u;
    float m = S[c]*invN;
    float var = S[256+c]*invN - m*m;
    float xv = (b2f((u16)tv[u]) - m) * rsqrtf(var + 1e-5f);
    if (relu) xv = fmaxf(xv, 0.f);
    ov[u] = (short)f2b(xv);
  }
  *reinterpret_cast<bh8*>(out + (size_t)r*rs_out + c8) = ov;
}

// ---------------- aggregation: 4 edges x 2 chains in flight, 8B chunks ----------------
// lane = (sub = lane>>4 : edge slot, chunk = lane&15 : 4-channel group)
// unroll-2: each sub runs two independent edge chains (e, e+4) -> 8 rows in flight/wave
#define ACC4(vv, ww) { \
    float c0 = __uint_as_float((vv).x << 16); \
    float c1 = __uint_as_float((vv).x & 0xffff0000u); \
    float c2 = __uint_as_float((vv).y << 16); \
    float c3 = __uint_as_float((vv).y & 0xffff0000u); \
    s0 += c0; s1 += c1; s2 += c2; s3 += c3; \
    n0 += c0*(ww); n1 += c1*(ww); n2 += c2*(ww); n3 += c3*(ww); }

template<int SHIFT>
__global__ __launch_bounds__(256) void k_aggv(const u16* h, const int* off, const int2* csr,
                                              const float* inv_sqrt, u16* out_sum, u16* out_norm, int Nn){
  int g = blockIdx.x*4 + (threadIdx.x >> 6);
  if (g >= Nn) return;
  int lane = threadIdx.x & 63;
  int sub = lane >> 4;
  int cb = (lane & 15) << 2;
  const u16* hp = h + cb;
  float s0=0.f,s1=0.f,s2=0.f,s3=0.f;
  float n0=0.f,n1=0.f,n2=0.f,n3=0.f;
  int e0 = off[g], e1 = off[g+1];
  int e = e0 + sub;
  for (; e + 4 < e1; e += 8){
    int2 cA = csr[e];
    int2 cB = csr[e+4];
    uint2 vA = *reinterpret_cast<const uint2*>(hp + (((unsigned)cA.x) << SHIFT));
    uint2 vB = *reinterpret_cast<const uint2*>(hp + (((unsigned)cB.x) << SHIFT));
    float wA = __int_as_float(cA.y), wB = __int_as_float(cB.y);
    ACC4(vA, wA)
    ACC4(vB, wB)
  }
  if (e < e1){
    int2 cA = csr[e];
    uint2 vA = *reinterpret_cast<const uint2*>(hp + (((unsigned)cA.x) << SHIFT));
    float wA = __int_as_float(cA.y);
    ACC4(vA, wA)
  }
  s0 += __shfl_xor(s0,16,64); s1 += __shfl_xor(s1,16,64);
  s2 += __shfl_xor(s2,16,64); s3 += __shfl_xor(s3,16,64);
  n0 += __shfl_xor(n0,16,64); n1 += __shfl_xor(n1,16,64);
  n2 += __shfl_xor(n2,16,64); n3 += __shfl_xor(n3,16,64);
  s0 += __shfl_xor(s0,32,64); s1 += __shfl_xor(s1,32,64);
  s2 += __shfl_xor(s2,32,64); s3 += __shfl_xor(s3,32,64);
  n0 += __shfl_xor(n0,32,64); n1 += __shfl_xor(n1,32,64);
  n2 += __shfl_xor(n2,32,64); n3 += __shfl_xor(n3,32,64);
  if (sub == 0){
    float ig = inv_sqrt[g];
    uint2 os, on;
    os.x = (uint)f2b(s0) | ((uint)f2b(s1) << 16);
    os.y = (uint)f2b(s2) | ((uint)f2b(s3) << 16);
    on.x = (uint)f2b(n0*ig) | ((uint)f2b(n1*ig) << 16);
    on.y = (uint)f2b(n2*ig) | ((uint)f2b(n3*ig) << 16);
    *reinterpret_cast<uint2*>(out_sum + (size_t)g*64 + cb) = os;
    *reinterpret_cast<uint2*>(out_norm + (size_t)g*64 + cb) = on;
  }
}

#define ACC4AB(va, vb, ww) { \
    float a0 = __uint_as_float((va).x << 16); \
    float a1 = __uint_as_float((va).x & 0xffff0000u); \
    float a2 = __uint_as_float((va).y << 16); \
    float a3 = __uint_as_float((va).y & 0xffff0000u); \
    float b0 = __uint_as_float((vb).x << 16); \
    float b1 = __uint_as_float((vb).x & 0xffff0000u); \
    float b2 = __uint_as_float((vb).y << 16); \
    float b3 = __uint_as_float((vb).y & 0xffff0000u); \
    sa0 += a0; sa1 += a1; sa2 += a2; sa3 += a3; \
    na0 += a0*(ww); na1 += a1*(ww); na2 += a2*(ww); na3 += a3*(ww); \
    sb0 += b0; sb1 += b1; sb2 += b2; sb3 += b3; \
    nb0 += b0*(ww); nb1 += b1*(ww); nb2 += b2*(ww); nb3 += b3*(ww); }

// dual-state over interleaved ab [N][128] (a at +0, b at +64)
__global__ __launch_bounds__(256) void k_agg2v(const u16* ab, const int* off, const int2* csr,
                                               const float* inv_sqrt,
                                               u16* os0, u16* on0, u16* os1, u16* on1, int Nn){
  int g = blockIdx.x*4 + (threadIdx.x >> 6);
  if (g >= Nn) return;
  int lane = threadIdx.x & 63;
  int sub = lane >> 4;
  int cb = (lane & 15) << 2;
  const u16* hp = ab + cb;
  float sa0=0.f,sa1=0.f,sa2=0.f,sa3=0.f, na0=0.f,na1=0.f,na2=0.f,na3=0.f;
  float sb0=0.f,sb1=0.f,sb2=0.f,sb3=0.f, nb0=0.f,nb1=0.f,nb2=0.f,nb3=0.f;
  int e0 = off[g], e1 = off[g+1];
  int e = e0 + sub;
  for (; e + 4 < e1; e += 8){
    int2 cA = csr[e];
    int2 cB = csr[e+4];
    const u16* rpA = hp + (((unsigned)cA.x) << 7);
    const u16* rpB = hp + (((unsigned)cB.x) << 7);
    uint2 vaA = *reinterpret_cast<const uint2*>(rpA);
    uint2 vbA = *reinterpret_cast<const uint2*>(rpA + 64);
    uint2 vaB = *reinterpret_cast<const uint2*>(rpB);
    uint2 vbB = *reinterpret_cast<const uint2*>(rpB + 64);
    float wA = __int_as_float(cA.y), wB = __int_as_float(cB.y);
    ACC4AB(vaA, vbA, wA)
    ACC4AB(vaB, vbB, wB)
  }
  if (e < e1){
    int2 cA = csr[e];
    const u16* rpA = hp + (((unsigned)cA.x) << 7);
    uint2 vaA = *reinterpret_cast<const uint2*>(rpA);
    uint2 vbA = *reinterpret_cast<const uint2*>(rpA + 64);
    float wA = __int_as_float(cA.y);
    ACC4AB(vaA, vbA, wA)
  }
  #pragma unroll
  for (int m = 16; m <= 32; m <<= 1){
    sa0 += __shfl_xor(sa0,m,64); sa1 += __shfl_xor(sa1,m,64);
    sa2 += __shfl_xor(sa2,m,64); sa3 += __shfl_xor(sa3,m,64);
    na0 += __shfl_xor(na0,m,64); na1 += __shfl_xor(na1,m,64);
    na2 += __shfl_xor(na2,m,64); na3 += __shfl_xor(na3,m,64);
    sb0 += __shfl_xor(sb0,m,64); sb1 += __shfl_xor(sb1,m,64);
    sb2 += __shfl_xor(sb2,m,64); sb3 += __shfl_xor(sb3,m,64);
    nb0 += __shfl_xor(nb0,m,64); nb1 += __shfl_xor(nb1,m,64);
    nb2 += __shfl_xor(nb2,m,64); nb3 += __shfl_xor(nb3,m,64);
  }
  if (sub == 0){
    float ig = inv_sqrt[g];
    uint2 v;
    v.x = (uint)f2b(sa0) | ((uint)f2b(sa1) << 16);
    v.y = (uint)f2b(sa2) | ((uint)f2b(sa3) << 16);
    *reinterpret_cast<uint2*>(os0 + (size_t)g*64 + cb) = v;
    v.x = (uint)f2b(na0*ig) | ((uint)f2b(na1*ig) << 16);
    v.y = (uint)f2b(na2*ig) | ((uint)f2b(na3*ig) << 16);
    *reinterpret_cast<uint2*>(on0 + (size_t)g*64 + cb) = v;
    v.x = (uint)f2b(sb0) | ((uint)f2b(sb1) << 16);
    v.y = (uint)f2b(sb2) | ((uint)f2b(sb3) << 16);
    *reinterpret_cast<uint2*>(os1 + (size_t)g*64 + cb) = v;
    v.x = (uint)f2b(nb0*ig) | ((uint)f2b(nb1*ig) << 16);
    v.y = (uint)f2b(nb2*ig) | ((uint)f2b(nb3*ig) << 16);
    *reinterpret_cast<uint2*>(on1 + (size_t)g*64 + cb) = v;
  }
}

// ---------------- fused mixed-op step ----------------
struct StepArgs {
  const u16* h[5]; const u16* asum[5]; const u16* anorm[5];
  int rs[5]; int slot[5]; int J;
  const u16* wpk; const float* inv_deg; const u16* x0;
  u16* out; int rs_out; int Nn;
};

__device__ __forceinline__ bh8 fr_scale(bh8 a, float s){
  bh8 r;
  #pragma unroll
  for (int i=0;i<8;i++) r[i] = (short)f2b(b2f((u16)a[i]) * s);
  return r;
}
__device__ __forceinline__ bh8 fr_add(bh8 a, bh8 b){
  bh8 r;
  #pragma unroll
  for (int i=0;i<8;i++) r[i] = (short)f2b(b2f((u16)a[i]) + b2f((u16)b[i]));
  return r;
}
__device__ __forceinline__ bh8 fr_comb(bh8 a, bh8 b, float wa, float wb){
  bh8 r;
  #pragma unroll
  for (int i=0;i<8;i++) r[i] = (short)f2b(wa*b2f((u16)a[i]) + wb*b2f((u16)b[i]));
  return r;
}

__device__ __forceinline__ void mm_acc(const bh8 (&af)[2][2], const u16* wlds, int mat,
                                       int t, int q, f4 (&oacc)[2][4]){
  #pragma unroll
  for (int kb=0;kb<2;kb++)
    #pragma unroll
    for (int nt=0;nt<4;nt++){
      bh8 bf = ld8(wlds + (mat<<12) + ((nt*16+t)<<6) + ((((kb<<2)|q) ^ (t&7))<<3));
      oacc[0][nt] = __builtin_amdgcn_mfma_f32_16x16x32_bf16(af[0][kb], bf, oacc[0][nt], 0, 0, 0);
      oacc[1][nt] = __builtin_amdgcn_mfma_f32_16x16x32_bf16(af[1][kb], bf, oacc[1][nt], 0, 0, 0);
    }
}

__device__ __forceinline__ void mm_relu(const bh8 (&af)[2][2], const u16* wlds, int mat,
                                        int t, int q, f4 (&oacc)[2][4]){
  f4 p[2][4];
  #pragma unroll
  for (int a=0;a<2;a++)
    #pragma unroll
    for (int b=0;b<4;b++) p[a][b] = (f4){0.f,0.f,0.f,0.f};
  #pragma unroll
  for (int kb=0;kb<2;kb++)
    #pragma unroll
    for (int nt=0;nt<4;nt++){
      bh8 bf = ld8(wlds + (mat<<12) + ((nt*16+t)<<6) + ((((kb<<2)|q) ^ (t&7))<<3));
      p[0][nt] = __builtin_amdgcn_mfma_f32_16x16x32_bf16(af[0][kb], bf, p[0][nt], 0, 0, 0);
      p[1][nt] = __builtin_amdgcn_mfma_f32_16x16x32_bf16(af[1][kb], bf, p[1][nt], 0, 0, 0);
    }
  #pragma unroll
  for (int rt=0;rt<2;rt++)
    #pragma unroll
    for (int nt=0;nt<4;nt++)
      #pragma unroll
      for (int r=0;r<4;r++)
        oacc[rt][nt][r] += fmaxf(p[rt][nt][r], 0.f);
}

__global__ __launch_bounds__(512) __attribute__((amdgpu_waves_per_eu(2,2)))
void k_step(StepArgs A){
  __shared__ u16 wlds[7*4096];   // 56 KB, XOR-swizzled 16B chunks
  int tid = threadIdx.x, wv = tid>>6, lane = tid&63, q = lane>>4, t = lane&15;
  int row0 = blockIdx.x*256 + wv*32;
  int rA0 = row0 + t, rA1 = row0 + 16 + t;
  int q8 = q*8;
  float idg0 = A.inv_deg[rA0];
  float idg1 = A.inv_deg[rA1];
  const u16* xp0 = A.x0 + (size_t)rA0*64;
  const u16* xp1 = A.x0 + (size_t)rA1*64;
  bh8 fx[2][2];
  fx[0][0]=ld8(xp0+q8); fx[0][1]=ld8(xp0+32+q8); fx[1][0]=ld8(xp1+q8); fx[1][1]=ld8(xp1+32+q8);

  f4 oacc[2][4];
  #pragma unroll
  for (int a=0;a<2;a++)
    #pragma unroll
    for (int b=0;b<4;b++) oacc[a][b] = (f4){0.f,0.f,0.f,0.f};

  for (int j = 0; j < A.J; ++j){
    __syncthreads();
    const u16* wg = A.wpk + ((size_t)A.slot[j]*7 << 12);
    for (int i = tid; i < 3584; i += 512){
      int mat = i >> 9, rem = i & 511, nn = rem >> 3, kc = rem & 7;
      uint4 vch = *reinterpret_cast<const uint4*>(wg + ((size_t)mat<<12) + (nn<<6) + (kc<<3));
      *reinterpret_cast<uint4*>(&wlds[(mat<<12) + (nn<<6) + ((kc ^ (nn&7))<<3)]) = vch;
    }
    __syncthreads();

    const u16* h = A.h[j]; int rs = A.rs[j];
    const u16* hp0 = h + (size_t)rA0*rs;
    const u16* hp1 = h + (size_t)rA1*rs;
    const u16* sp0 = A.asum[j] + (size_t)rA0*64;
    const u16* sp1 = A.asum[j] + (size_t)rA1*64;
    const u16* np0 = A.anorm[j] + (size_t)rA0*64;
    const u16* np1 = A.anorm[j] + (size_t)rA1*64;

    bh8 fh[2][2], fs[2][2], ax[2][2];

    fh[0][0]=ld8(hp0+q8); fh[0][1]=ld8(hp0+32+q8); fh[1][0]=ld8(hp1+q8); fh[1][1]=ld8(hp1+32+q8);
    mm_acc(fh, wlds, 1, t, q, oacc);
    mm_relu(fh, wlds, 5, t, q, oacc);
    fs[0][0]=ld8(sp0+q8); fs[0][1]=ld8(sp0+32+q8); fs[1][0]=ld8(sp1+q8); fs[1][1]=ld8(sp1+32+q8);
    mm_acc(fs, wlds, 4, t, q, oacc);
    ax[0][0]=fr_scale(fs[0][0], idg0); ax[0][1]=fr_scale(fs[0][1], idg0);
    ax[1][0]=fr_scale(fs[1][0], idg1); ax[1][1]=fr_scale(fs[1][1], idg1);
    mm_acc(ax, wlds, 2, t, q, oacc);
    ax[0][0]=fr_add(fh[0][0], fs[0][0]); ax[0][1]=fr_add(fh[0][1], fs[0][1]);
    ax[1][0]=fr_add(fh[1][0], fs[1][0]); ax[1][1]=fr_add(fh[1][1], fs[1][1]);
    mm_relu(ax, wlds, 3, t, q, oacc);
    fs[0][0]=ld8(np0+q8); fs[0][1]=ld8(np0+32+q8); fs[1][0]=ld8(np1+q8); fs[1][1]=ld8(np1+32+q8);
    mm_relu(fs, wlds, 0, t, q, oacc);
    ax[0][0]=fr_comb(fs[0][0], fx[0][0], 0.9f, 0.1f);
    ax[0][1]=fr_comb(fs[0][1], fx[0][1], 0.9f, 0.1f);
    ax[1][0]=fr_comb(fs[1][0], fx[1][0], 0.9f, 0.1f);
    ax[1][1]=fr_comb(fs[1][1], fx[1][1], 0.9f, 0.1f);
    mm_relu(ax, wlds, 6, t, q, oacc);
  }

  #pragma unroll
  for (int rt=0;rt<2;rt++)
    #pragma unroll
    for (int nt=0;nt<4;nt++)
      #pragma unroll
      for (int r=0;r<4;r++){
        int rr = row0 + rt*16 + q*4 + r;
        if (rr < A.Nn) A.out[(size_t)rr*A.rs_out + nt*16 + t] = f2b(oacc[rt][nt][r]);
      }
}

// ---------------- classifier: MFMA GEMM [N,256]x[256,48] with bias ----------------
__global__ __launch_bounds__(256) void k_cls_mm(const u16* A, const u16* Bp,
                                                const float* bvec, float* out, int Nn){
  int tid = threadIdx.x, wv = tid>>6, lane = tid&63, q = lane>>4, t = lane&15;
  int row0 = blockIdx.x*128 + wv*32;
  f4 acc[2][3];
  #pragma unroll
  for (int a=0;a<2;a++)
    #pragma unroll
    for (int b=0;b<3;b++) acc[a][b] = (f4){0.f,0.f,0.f,0.f};
  const u16* arow0 = A + (size_t)(row0 + t)*256 + q*8;
  const u16* arow1 = arow0 + (size_t)16*256;
  const u16* brow  = Bp + (size_t)t*256 + q*8;
  #pragma unroll
  for (int kb = 0; kb < 8; ++kb){
    bh8 a0 = ld8(arow0 + kb*32);
    bh8 a1 = ld8(arow1 + kb*32);
    #pragma unroll
    for (int nt=0; nt<3; ++nt){
      bh8 bf = ld8(brow + (size_t)nt*16*256 + kb*32);
      acc[0][nt] = __builtin_amdgcn_mfma_f32_16x16x32_bf16(a0, bf, acc[0][nt], 0, 0, 0);
      acc[1][nt] = __builtin_amdgcn_mfma_f32_16x16x32_bf16(a1, bf, acc[1][nt], 0, 0, 0);
    }
  }
  #pragma unroll
  for (int rt=0;rt<2;rt++)
    #pragma unroll
    for (int nt=0;nt<3;nt++){
      int col = nt*16 + t;
      #pragma unroll
      for (int r=0;r<4;r++){
        int row = row0 + rt*16 + q*4 + r;
        if (row < Nn && col < 40) out[(size_t)row*40 + col] = acc[rt][nt][r] + bvec[col];
      }
    }
}

// ---------------- host ----------------
extern "C" void kernel_launch(void* const* d_in, const int* in_sizes, int n_in,
                              void* d_out, int out_size, void* d_ws, size_t ws_size,
                              hipStream_t stream){
  (void)n_in; (void)out_size; (void)ws_size;
  const float* x      = (const float*)d_in[0];
  const int*   ei     = (const int*)d_in[1];
  const float* alphas = (const float*)d_in[2];
  const float* stem_W = (const float*)d_in[3];
  const float* pre_W  = (const float*)d_in[4];
  const float* p00    = (const float*)d_in[5];
  const float* p10    = (const float*)d_in[6];
  const float* p01    = (const float*)d_in[7];
  const float* p11    = (const float*)d_in[8];
  const float* clsW = (const float*)d_in[17];
  const float* clsb = (const float*)d_in[18];

  int N = in_sizes[0] / 128;
  int E = in_sizes[1] / 2;
  const int* esrc = ei;
  const int* edst = ei + E;

  char* p = (char*)d_ws;
  auto carve = [&](size_t bytes) -> char* {
    char* r = p; p += (bytes + 255) & ~(size_t)255; return r;
  };
  int*   deg     = (int*)carve((size_t)N*4);
  int*   off     = (int*)carve((size_t)(N+1)*4);
  int*   cursor  = (int*)carve((size_t)N*4);
  int2*  csr     = (int2*)carve((size_t)E*8);
  float* inv_deg = (float*)carve((size_t)N*4);
  float* invs    = (float*)carve((size_t)N*4);
  float* wmix    = (float*)carve(14*8*4);
  float* stats   = (float*)carve(512*4);
  u16* xb      = (u16*)carve((size_t)N*128*2);
  u16* stem_pk = (u16*)carve((size_t)192*128*2);
  u16* pre_pk  = (u16*)carve((size_t)64*128*2);
  u16* p00_pk  = (u16*)carve((size_t)64*192*2);
  u16* p10_pk  = (u16*)carve((size_t)64*192*2);
  u16* p01_pk  = (u16*)carve((size_t)64*192*2);
  u16* p11_pk  = (u16*)carve((size_t)64*256*2);
  u16* cls_pk  = (u16*)carve((size_t)48*256*2);
  u16* ops_pk  = (u16*)carve((size_t)28*7*4096*2);
  u16* T       = (u16*)carve((size_t)N*192*2);
  u16* stem_o  = (u16*)carve((size_t)N*192*2);
  u16* x0b     = (u16*)carve((size_t)N*64*2);
  u16* ab      = (u16*)carve((size_t)N*128*2);
  u16* oc0     = (u16*)carve((size_t)N*256*2);
  u16* oc1     = (u16*)carve((size_t)N*256*2);
  u16* agg     = (u16*)carve((size_t)5*2*N*64*2);
  carve(131072); // tail slack for unguarded OOB-row reads

  auto aggS = [&](int j){ return agg + (size_t)j*2*N*64; };
  auto aggN = [&](int j){ return agg + (size_t)j*2*N*64 + (size_t)N*64; };

  int eg = (E + 255)/256;
  int ng = (N + 255)/256;
  int gg = (N + 127)/128;
  int gg2 = (N + 255)/256;
  int ag = (N + 3)/4;
  float invN = 1.0f/(float)N;

  hipMemsetAsync(deg, 0, (size_t)N*4, stream);
  k_count_deg<<<eg,256,0,stream>>>(edst, deg, E);
  k_scan<<<1,1024,0,stream>>>(deg, off, N);
  k_invdeg<<<ng,256,0,stream>>>(deg, off, cursor, inv_deg, invs, N);
  k_fill_csr<<<eg,256,0,stream>>>(esrc, edst, invs, cursor, csr, E);
  k_softmax<<<1,128,0,stream>>>(alphas, wmix);
  k_f2b<<<(N*128+255)/256,256,0,stream>>>(x, xb, N*128);
  k_pack2d<<<(128*192+255)/256,256,0,stream>>>(stem_W, stem_pk, 128, 192);
  k_pack2d<<<(128*64+255)/256,256,0,stream>>>(pre_W, pre_pk, 128, 64);
  k_pack2d<<<(192*64+255)/256,256,0,stream>>>(p00, p00_pk, 192, 64);
  k_pack2d<<<(192*64+255)/256,256,0,stream>>>(p10, p10_pk, 192, 64);
  k_pack2d<<<(192*64+255)/256,256,0,stream>>>(p01, p01_pk, 192, 64);
  k_pack2d<<<(256*64+255)/256,256,0,stream>>>(p11, p11_pk, 256, 64);
  k_pack_cls<<<(48*256+255)/256,256,0,stream>>>(clsW, cls_pk);
  {
    PackArgs PA;
    for (int i = 0; i < 8; ++i) PA.W[i] = (const float*)d_in[9+i];
    PA.wmix = wmix; PA.dst = ops_pk;
    k_pack_ops7<<<(28*7*4096+255)/256,256,0,stream>>>(PA);
  }

  auto mlp = [&](const u16* A, int lda, const u16* Bp, int K, int ncol, u16* outb, int rs_out, int relu){
    hipMemsetAsync(stats, 0, 512*4, stream);
    if (ncol == 192)
      hipLaunchKernelGGL(HIP_KERNEL_NAME(k_gemm<12>), dim3(gg), dim3(256), 0, stream, A, lda, Bp, K, T, ncol, N, stats);
    else
      hipLaunchKernelGGL(HIP_KERNEL_NAME(k_gemm<4>), dim3(gg), dim3(256), 0, stream, A, lda, Bp, K, T, ncol, N, stats);
    k_norm<<<((N*(ncol>>3))+255)/256,256,0,stream>>>(T, ncol, ncol, N, stats, outb, rs_out, relu, invN);
  };

  // stem (no relu) and preprocess (relu)
  mlp(xb, 128, stem_pk, 128, 192, stem_o, 192, 0);
  mlp(xb, 128, pre_pk, 128, 64, x0b, 64, 1);

  u16* ocs[2] = {oc0, oc1};
  const int slotbase[4] = {0, 2, 5, 9};
  for (int ci = 0; ci < 2; ++ci){
    const u16* s1in = (ci == 0) ? stem_o : oc0;
    int lda1 = (ci == 0) ? 192 : 256;
    int Kb   = (ci == 0) ? 192 : 256;
    const u16* pa = (ci == 0) ? p00_pk : p01_pk;
    const u16* pb = (ci == 0) ? p10_pk : p11_pk;
    mlp(stem_o, 192, pa, 192, 64, ab, 128, 1);        // a -> ab[:, 0:64]
    mlp(s1in, lda1, pb, Kb, 64, ab + 64, 128, 1);     // b -> ab[:, 64:128]

    u16* oc = ocs[ci];
    const u16* wpk_cell = ops_pk + (size_t)ci*14*7*4096;

    k_agg2v<<<ag,256,0,stream>>>(ab, off, csr, invs,
                                 aggS(0), aggN(0), aggS(1), aggN(1), N);

    const u16* st[5] = { ab, ab + 64, oc + 0, oc + 64, oc + 128 };
    const int strs[5] = {128, 128, 256, 256, 256};
    for (int step = 0; step < 4; ++step){
      StepArgs SA{};
      int J = step + 2;
      for (int j = 0; j < J; ++j){
        SA.h[j] = st[j]; SA.rs[j] = strs[j];
        SA.asum[j] = aggS(j); SA.anorm[j] = aggN(j);
        SA.slot[j] = slotbase[step] + j;
      }
      SA.J = J; SA.wpk = wpk_cell; SA.inv_deg = inv_deg; SA.x0 = x0b;
      SA.out = oc + (size_t)step*64; SA.rs_out = 256; SA.Nn = N;
      k_step<<<gg2,512,0,stream>>>(SA);
      if (step < 3)
        hipLaunchKernelGGL(HIP_KERNEL_NAME(k_aggv<8>), dim3(ag), dim3(256), 0, stream,
                           oc + (size_t)step*64, off, csr, invs, aggS(step+2), aggN(step+2), N);
    }
  }

  k_cls_mm<<<gg,256,0,stream>>>(oc1, cls_pk, clsb, (float*)d_out, N);
}